// Round 1
// baseline (1404.976 us; speedup 1.0000x reference)
//
#include <hip/hip_runtime.h>
#include <cstdint>
#include <cstddef>

#define TT 2048
#define BB 32
#define DD 256
#define HH 256
#define G3 768   // 3*H

// ws layout:
// [0]  int   : record-count / nseg (atomic)
// [1]  int   : queue head (atomic)
// [64 ..)    : int4 records, up to 65536
// [WT_OFF ..): transposed weights, k-major: WT[2][256][768] f32
static const size_t REC_OFF = 64;
static const size_t WT_OFF  = 64 + (size_t)65536 * 16;   // 1 MiB + 64

// ---------------- transpose W to k-major ----------------
__global__ void k_transpose(const float* __restrict__ Wih,
                            const float* __restrict__ Whh,
                            float* __restrict__ WT) {
    int o = blockIdx.x * 256 + threadIdx.x;        // output-linear index
    if (o >= 2 * DD * G3) return;
    int which = o / (DD * G3);
    int r = o - which * (DD * G3);
    int k = r / G3;
    int j = r - k * G3;
    const float* W = which ? Whh : Wih;            // [G3][DD], j-major
    WT[o] = W[j * DD + k];
}

// ---------------- per-batch segment metadata ----------------
__global__ void k_meta(const int* __restrict__ seg, const int* __restrict__ lengths,
                       int4* __restrict__ recs, int* __restrict__ counters,
                       float* __restrict__ outIdx) {
    int b = blockIdx.x;
    int tid = threadIdx.x;                          // 256 threads
    int len = lengths[b];
    const int* s = seg + (size_t)b * TT;
    const int CH = TT / 256;                        // 8
    int t0 = tid * CH;

    int cnt = 0;
    for (int t = t0; t < t0 + CH; ++t)
        cnt += (s[t] == 0 && t < len) ? 1 : 0;

    __shared__ int part[256];
    __shared__ int base;
    part[tid] = cnt;
    __syncthreads();
    if (tid == 0) {
        int run = 0;
        for (int i = 0; i < 256; ++i) { int v = part[i]; part[i] = run; run += v; }
        base = atomicAdd(&counters[0], run);        // global slot base; counters[0] ends = nseg
        outIdx[b] = (float)run;                     // idx[b] output (as float)
    }
    __syncthreads();

    int run = part[tid];                            // within-batch exclusive rank
    for (int t = t0; t < t0 + CH; ++t) {
        if (s[t] == 0 && t < len) {
            int ss = t - 1;
            while (ss >= 0 && s[ss] != 0) --ss;     // previous boundary (any, incl. dead)
            recs[base + run] = make_int4(b, ss + 1, t, run);
            ++run;
        }
    }
}

// ---------------- persistent segment-packed GRU ----------------
__global__ __launch_bounds__(512, 2) void k_main(
    const float* __restrict__ x, const float* __restrict__ WT,
    const float* __restrict__ b_ih, const float* __restrict__ b_hh,
    const int4* __restrict__ recs, int* __restrict__ counters,
    float* __restrict__ out)
{
    __shared__ float hS[8][DD];      // hidden state per row slot
    __shared__ float xS[8][DD];      // staged x row per slot
    __shared__ float bIS[G3], bHS[G3];
    __shared__ int rb[8], rt[8], re[8], rp[8], alive[8];
    __shared__ int anyAlive;
    __shared__ int nsegS;

    int tid = threadIdx.x;
    int c  = tid & 255;              // output column 0..255
    int mg = tid >> 8;               // row half: 0 -> rows 0..3, 1 -> rows 4..7

    for (int i = tid; i < G3; i += 512) { bIS[i] = b_ih[i]; bHS[i] = b_hh[i]; }
    for (int i = tid; i < 8 * DD; i += 512) ((float*)hS)[i] = 0.f;
    if (tid < 8) alive[tid] = 0;
    if (tid == 0) nsegS = counters[0];
    __syncthreads();
    const int nseg = nsegS;
    const float* WTi = WT;
    const float* WTh = WT + DD * G3;

    for (;;) {
        // ---- U phase: advance / pop ----
        if (tid < 8) {
            int m = tid;
            if (alive[m]) {
                if (rt[m] >= re[m]) alive[m] = 0;   // finished last step previous iter
                else rt[m]++;
            }
            if (!alive[m]) {
                int sidx = atomicAdd(&counters[1], 1);
                if (sidx < nseg) {
                    int4 r = recs[sidx];
                    rb[m] = r.x; rt[m] = r.y; re[m] = r.z; rp[m] = r.w;
                    alive[m] = 1;                   // h[m][*] is already zero
                }
            }
        }
        __syncthreads();
        if (tid == 0) { int a = 0; for (int m = 0; m < 8; ++m) a |= alive[m]; anyAlive = a; }
        // stage x rows (64 threads x float4 per row)
        {
            int m2 = tid >> 6;
            int q  = (tid & 63) << 2;
            if (alive[m2]) {
                const float* xp = x + ((size_t)rb[m2] * TT + rt[m2]) * DD + q;
                float4 v = *(const float4*)xp;
                *(float4*)&xS[m2][q] = v;
            }
        }
        __syncthreads();
        if (!anyAlive) break;

        int live4 = alive[mg*4] | alive[mg*4+1] | alive[mg*4+2] | alive[mg*4+3];

        float accI[4][3] = {{0.f,0.f,0.f},{0.f,0.f,0.f},{0.f,0.f,0.f},{0.f,0.f,0.f}};
        float accH[4][3] = {{0.f,0.f,0.f},{0.f,0.f,0.f},{0.f,0.f,0.f},{0.f,0.f,0.f}};

        if (live4) {
            #pragma unroll 4
            for (int k = 0; k < DD; ++k) {
                float wi0 = WTi[k * G3 + c];
                float wi1 = WTi[k * G3 + 256 + c];
                float wi2 = WTi[k * G3 + 512 + c];
                float wh0 = WTh[k * G3 + c];
                float wh1 = WTh[k * G3 + 256 + c];
                float wh2 = WTh[k * G3 + 512 + c];
                #pragma unroll
                for (int i = 0; i < 4; ++i) {
                    float xv = xS[mg*4 + i][k];
                    float hv = hS[mg*4 + i][k];
                    accI[i][0] += xv * wi0; accI[i][1] += xv * wi1; accI[i][2] += xv * wi2;
                    accH[i][0] += hv * wh0; accH[i][1] += hv * wh1; accH[i][2] += hv * wh2;
                }
            }
        }
        __syncthreads();   // all h reads done before overwrite

        if (live4) {
            #pragma unroll
            for (int i = 0; i < 4; ++i) {
                int m = mg*4 + i;
                if (!alive[m]) continue;
                float gr = accI[i][0] + bIS[c]       + accH[i][0] + bHS[c];
                float gz = accI[i][1] + bIS[c + 256] + accH[i][1] + bHS[c + 256];
                float gn = accI[i][2] + bIS[c + 512];
                float hg = accH[i][2] + bHS[c + 512];
                float r = 1.f / (1.f + expf(-gr));
                float z = 1.f / (1.f + expf(-gz));
                float n = tanhf(gn + r * hg);
                float hold = hS[m][c];
                float hnew = (1.f - z) * n + z * hold;
                if (rt[m] == re[m]) {
                    out[((size_t)rb[m] * TT + rp[m]) * HH + c] = hnew;  // boundary: emit
                    hS[m][c] = 0.f;                                      // reset for next segment
                } else {
                    hS[m][c] = hnew;
                }
            }
        }
        __syncthreads();   // gate writes done before next U-phase metadata update
    }
}

extern "C" void kernel_launch(void* const* d_in, const int* in_sizes, int n_in,
                              void* d_out, int out_size, void* d_ws, size_t ws_size,
                              hipStream_t stream) {
    const float* x   = (const float*)d_in[0];
    const int*   seg = (const int*)d_in[1];
    const int*   len = (const int*)d_in[2];
    const float* Wih = (const float*)d_in[3];
    const float* Whh = (const float*)d_in[4];
    const float* bih = (const float*)d_in[5];
    const float* bhh = (const float*)d_in[6];
    float* out = (float*)d_out;

    int*  counters = (int*)d_ws;
    int4* recs     = (int4*)((char*)d_ws + REC_OFF);
    float* WT      = (float*)((char*)d_ws + WT_OFF);

    hipMemsetAsync(d_out, 0, (size_t)out_size * sizeof(float), stream);
    hipMemsetAsync(d_ws, 0, 64, stream);

    k_transpose<<<(2 * DD * G3 + 255) / 256, 256, 0, stream>>>(Wih, Whh, WT);
    k_meta<<<BB, 256, 0, stream>>>(seg, len, recs, counters, out + (size_t)BB * TT * HH);
    k_main<<<256, 512, 0, stream>>>(x, WT, bih, bhh, recs, counters, out);
}

// Round 2
// 740.965 us; speedup vs baseline: 1.8961x; 1.8961x over previous
//
#include <hip/hip_runtime.h>
#include <cstdint>
#include <cstddef>

#define TT 2048
#define BB 32
#define DD 256
#define HH 256
#define G3 768   // 3*H

using bf16x8 = __attribute__((ext_vector_type(8))) short;
using f32x4  = __attribute__((ext_vector_type(4))) float;

// ws layout:
// [0..63]    : counters (int): [0]=nseg, [1]=queue head
// [64..)     : int4 records (<= 65536)
// [BIH_OFF..): W_ih as bf16 [768][256] (j-major, k-contiguous)
// [BHH_OFF..): W_hh as bf16 [768][256]
static const size_t REC_OFF = 64;
static const size_t BIH_OFF = 64 + (size_t)65536 * 16;            // 1 MiB + 64
static const size_t BHH_OFF = BIH_OFF + (size_t)G3 * DD * 2;      // + 384 KiB

__device__ __forceinline__ uint16_t f2bf(float v) {
    unsigned int u = __float_as_uint(v);
    u += 0x7FFF + ((u >> 16) & 1);          // RNE
    return (uint16_t)(u >> 16);
}
__device__ __forceinline__ float bf2f(uint16_t h) {
    return __uint_as_float(((unsigned int)h) << 16);
}
__device__ __forceinline__ float sigmoidf_(float v) {
    return 1.f / (1.f + __expf(-v));
}
__device__ __forceinline__ float tanhf_(float v) {
    v = fminf(fmaxf(v, -30.f), 30.f);
    float e = __expf(-2.f * v);
    return (1.f - e) / (1.f + e);
}

// ---------------- weights f32 -> bf16 ----------------
__global__ void k_prep(const float* __restrict__ Wih, const float* __restrict__ Whh,
                       uint16_t* __restrict__ Bih, uint16_t* __restrict__ Bhh) {
    int i = blockIdx.x * 256 + threadIdx.x;
    if (i < G3 * DD) { Bih[i] = f2bf(Wih[i]); Bhh[i] = f2bf(Whh[i]); }
}

// ---------------- per-batch segment metadata ----------------
__global__ void k_meta(const int* __restrict__ seg, const int* __restrict__ lengths,
                       int4* __restrict__ recs, int* __restrict__ counters,
                       float* __restrict__ outIdx) {
    int b = blockIdx.x;
    int tid = threadIdx.x;                          // 256 threads
    int len = lengths[b];
    const int* s = seg + (size_t)b * TT;
    const int CH = TT / 256;                        // 8
    int t0 = tid * CH;

    int cnt = 0;
    for (int t = t0; t < t0 + CH; ++t)
        cnt += (s[t] == 0 && t < len) ? 1 : 0;

    __shared__ int part[256];
    __shared__ int base;
    part[tid] = cnt;
    __syncthreads();
    if (tid == 0) {
        int run = 0;
        for (int i = 0; i < 256; ++i) { int v = part[i]; part[i] = run; run += v; }
        base = atomicAdd(&counters[0], run);
        outIdx[b] = (float)run;                     // idx[b] output (as float)
    }
    __syncthreads();

    int run = part[tid];
    for (int t = t0; t < t0 + CH; ++t) {
        if (s[t] == 0 && t < len) {
            int ss = t - 1;
            while (ss >= 0 && s[ss] != 0) --ss;     // previous boundary (any, incl. dead)
            recs[base + run] = make_int4(b, ss + 1, t, run);
            ++run;
        }
    }
}

// ---------------- persistent MFMA segment-packed GRU ----------------
// 512 thr = 8 waves; M=16 slots; wave w owns H-cols [w*32, w*32+32).
// acc[gate][ct]: gate 0=r,1=z,2=i_n,3=h_n ; ct = col-subtile (16 cols each).
__global__ __launch_bounds__(512) void k_main(
    const float* __restrict__ x,
    const uint16_t* __restrict__ Bih, const uint16_t* __restrict__ Bhh,
    const float* __restrict__ b_ih, const float* __restrict__ b_hh,
    const int4* __restrict__ recs, int* __restrict__ counters,
    float* __restrict__ out)
{
    __shared__ __attribute__((aligned(16))) uint16_t xAhi[16 * 256];
    __shared__ __attribute__((aligned(16))) uint16_t xAlo[16 * 256];
    __shared__ __attribute__((aligned(16))) uint16_t hAhi[16 * 256];
    __shared__ __attribute__((aligned(16))) uint16_t hAlo[16 * 256];
    __shared__ int rb[16], rt[16], re[16], rp[16], alive[16];
    __shared__ int anyAliveS, nsegS;

    const int tid  = threadIdx.x;
    const int lane = tid & 63;
    const int w    = tid >> 6;           // wave 0..7
    const int lcol = lane & 15;          // A row / C col / B col within tile
    const int lk8  = (lane >> 4) << 3;   // k base within 32-wide K window
    const int lrow4 = (lane >> 4) << 2;  // C row base

    for (int i = tid; i < 16 * 256; i += 512) { hAhi[i] = 0; hAlo[i] = 0; }
    if (tid < 16) { alive[tid] = 0; rb[tid] = 0; rt[tid] = 0; re[tid] = -1; rp[tid] = 0; }
    if (tid == 0) nsegS = counters[0];
    __syncthreads();
    const int nseg = nsegS;

    // per-lane combined biases for its 2 col-subtiles
    float bR[2], bZ[2], bIN[2], bHN[2];
    #pragma unroll
    for (int ct = 0; ct < 2; ++ct) {
        int c = w * 32 + ct * 16 + lcol;
        bR[ct]  = b_ih[c]       + b_hh[c];
        bZ[ct]  = b_ih[256 + c] + b_hh[256 + c];
        bIN[ct] = b_ih[512 + c];
        bHN[ct] = b_hh[512 + c];
    }
    float hm[2][4] = {{0.f,0.f,0.f,0.f},{0.f,0.f,0.f,0.f}};   // f32 master h

    const int srow = tid >> 5;           // x-stage: row 0..15
    const int scs  = tid & 31;           // x-stage: 8-elem chunk 0..31

    for (;;) {
        // ---- slot advance / pop ----
        if (tid < 16) {
            int m = tid;
            if (alive[m]) { if (rt[m] >= re[m]) alive[m] = 0; else rt[m]++; }
            if (!alive[m]) {
                int sidx = atomicAdd(&counters[1], 1);
                if (sidx < nseg) {
                    int4 r = recs[sidx];
                    rb[m] = r.x; rt[m] = r.y; re[m] = r.z; rp[m] = r.w;
                    alive[m] = 1;                    // h rows are zero already
                }
            }
        }
        __syncthreads();
        if (tid == 0) { int a = 0; for (int m = 0; m < 16; ++m) a |= alive[m]; anyAliveS = a; }
        // ---- stage x rows (load f32, split to bf16 hi/lo, swizzled LDS) ----
        if (alive[srow]) {
            const float* xp = x + ((size_t)rb[srow] * TT + rt[srow]) * DD + scs * 8;
            float4 v0 = *(const float4*)xp;
            float4 v1 = *(const float4*)(xp + 4);
            float vv[8] = {v0.x, v0.y, v0.z, v0.w, v1.x, v1.y, v1.z, v1.w};
            bf16x8 vh, vl;
            #pragma unroll
            for (int j = 0; j < 8; ++j) {
                uint16_t h = f2bf(vv[j]);
                vh[j] = (short)h;
                vl[j] = (short)f2bf(vv[j] - bf2f(h));
            }
            int base = srow * 256 + ((scs ^ (srow & 7)) << 3);
            *(bf16x8*)&xAhi[base] = vh;
            *(bf16x8*)&xAlo[base] = vl;
        }
        __syncthreads();
        if (!anyAliveS) break;

        // ---- MFMA phase: acc = [x;h] x [Bih;Bhh] ----
        f32x4 acc[4][2];
        #pragma unroll
        for (int g = 0; g < 4; ++g)
            #pragma unroll
            for (int ct = 0; ct < 2; ++ct)
                acc[g][ct] = (f32x4){0.f, 0.f, 0.f, 0.f};

        for (int kk = 0; kk < 8; ++kk) {
            int cs = (kk << 2) + (lane >> 4);
            int aoff = lcol * 256 + ((cs ^ (lcol & 7)) << 3);
            bf16x8 axh = *(const bf16x8*)&xAhi[aoff];
            bf16x8 axl = *(const bf16x8*)&xAlo[aoff];
            bf16x8 ahh = *(const bf16x8*)&hAhi[aoff];
            bf16x8 ahl = *(const bf16x8*)&hAlo[aoff];
            int bbase = (w * 32 + lcol) * 256 + (kk << 5) + lk8;
            #pragma unroll
            for (int g = 0; g < 3; ++g) {
                #pragma unroll
                for (int ct = 0; ct < 2; ++ct) {
                    bf16x8 bf = *(const bf16x8*)&Bih[bbase + g * 65536 + ct * 4096];
                    acc[g][ct] = __builtin_amdgcn_mfma_f32_16x16x32_bf16(axh, bf, acc[g][ct], 0, 0, 0);
                    acc[g][ct] = __builtin_amdgcn_mfma_f32_16x16x32_bf16(axl, bf, acc[g][ct], 0, 0, 0);
                }
            }
            #pragma unroll
            for (int g = 0; g < 3; ++g) {
                const int ai = (g == 2) ? 3 : g;     // h_n accumulates separately
                #pragma unroll
                for (int ct = 0; ct < 2; ++ct) {
                    bf16x8 bf = *(const bf16x8*)&Bhh[bbase + g * 65536 + ct * 4096];
                    acc[ai][ct] = __builtin_amdgcn_mfma_f32_16x16x32_bf16(ahh, bf, acc[ai][ct], 0, 0, 0);
                    acc[ai][ct] = __builtin_amdgcn_mfma_f32_16x16x32_bf16(ahl, bf, acc[ai][ct], 0, 0, 0);
                }
            }
        }
        __syncthreads();   // all hA reads done before gate phase rewrites it

        // ---- gates + emit + h update ----
        #pragma unroll
        for (int ct = 0; ct < 2; ++ct) {
            int c = w * 32 + ct * 16 + lcol;
            #pragma unroll
            for (int q = 0; q < 4; ++q) {
                int row = lrow4 + q;
                float gr  = acc[0][ct][q] + bR[ct];
                float gz  = acc[1][ct][q] + bZ[ct];
                float gin = acc[2][ct][q] + bIN[ct];
                float ghn = acc[3][ct][q] + bHN[ct];
                float r = sigmoidf_(gr);
                float z = sigmoidf_(gz);
                float n = tanhf_(gin + r * ghn);
                float hnew = (1.f - z) * n + z * hm[ct][q];
                int al = alive[row];
                int em = al && (rt[row] == re[row]);
                if (em) out[((size_t)rb[row] * TT + rp[row]) * HH + c] = hnew;
                hnew = em ? 0.f : hnew;
                if (al) {
                    hm[ct][q] = hnew;
                    uint16_t hh = f2bf(hnew);
                    uint16_t hl = f2bf(hnew - bf2f(hh));
                    int idx = row * 256 + ((((c >> 3)) ^ (row & 7)) << 3) + (c & 7);
                    hAhi[idx] = hh; hAlo[idx] = hl;
                }
            }
        }
        __syncthreads();   // hA writes + meta stable before next pop
    }
}

extern "C" void kernel_launch(void* const* d_in, const int* in_sizes, int n_in,
                              void* d_out, int out_size, void* d_ws, size_t ws_size,
                              hipStream_t stream) {
    const float* x   = (const float*)d_in[0];
    const int*   seg = (const int*)d_in[1];
    const int*   len = (const int*)d_in[2];
    const float* Wih = (const float*)d_in[3];
    const float* Whh = (const float*)d_in[4];
    const float* bih = (const float*)d_in[5];
    const float* bhh = (const float*)d_in[6];
    float* out = (float*)d_out;

    int*      counters = (int*)d_ws;
    int4*     recs     = (int4*)((char*)d_ws + REC_OFF);
    uint16_t* Bih      = (uint16_t*)((char*)d_ws + BIH_OFF);
    uint16_t* Bhh      = (uint16_t*)((char*)d_ws + BHH_OFF);

    hipMemsetAsync(d_out, 0, (size_t)out_size * sizeof(float), stream);
    hipMemsetAsync(d_ws, 0, 64, stream);

    k_prep<<<(G3 * DD + 255) / 256, 256, 0, stream>>>(Wih, Whh, Bih, Bhh);
    k_meta<<<BB, 256, 0, stream>>>(seg, len, recs, counters, out + (size_t)BB * TT * HH);
    k_main<<<512, 512, 0, stream>>>(x, Bih, Bhh, bih, bhh, recs, counters, out);
}